// Round 4
// baseline (501.969 us; speedup 1.0000x reference)
//
#include <hip/hip_runtime.h>
#include <math.h>
#include <float.h>

// VideoQuantizer: rmsnorm -> per-subvector argmin over 4096 codewords -> gather -> rmsnorm
// B=8 T=1024 D=1024 Q=8 K=4096 d=128
#define Q_     8
#define K_     4096
#define dd_    128
#define D_     1024
#define ROWS   8192
#define NCHUNK 64
#define TAU    0.01f   // rescue threshold on d2/2 scale (err ~2.5e-3 + quant ~2e-3)

typedef __attribute__((ext_vector_type(8))) short bf16x8;
typedef __attribute__((ext_vector_type(4))) float f32x4;
typedef __attribute__((ext_vector_type(4))) unsigned int u32x4;

typedef const __attribute__((address_space(1))) unsigned int* gas_p;
typedef __attribute__((address_space(3))) unsigned int* las_p;

__device__ inline float bf2f(unsigned short h) {
    union { unsigned u; float f; } v; v.u = ((unsigned)h) << 16; return v.f;
}
__device__ inline unsigned f2u(float x) { union { float f; unsigned u; } v; v.f = x; return v.u; }
__device__ inline float u2f(unsigned x) { union { unsigned u; float f; } v; v.u = x; return v.f; }
__device__ inline unsigned umin_(unsigned a, unsigned b) { return a < b ? a : b; }
__device__ inline unsigned umax_(unsigned a, unsigned b) { return a > b ? a : b; }

// ---------------- fused: panel build (neg, hi/lo trunc split) + c2/2 | input rmsnorm + x2/2 ----
// panels[q][c][plane][n][slot][8 bf16] of NEGATED codewords; slot = j ^ (n&15)
__global__ void k_prep(const float* __restrict__ cb, const float* __restrict__ x,
                       const float* __restrict__ w, float* __restrict__ xn,
                       unsigned short* __restrict__ panels, float* __restrict__ c2h,
                       float* __restrict__ x2h) {
    const int bid = blockIdx.x, t = threadIdx.x;
    if (bid < NCHUNK * Q_) {
        // ---- panel prep ----
        int c = bid & 63, q = bid >> 6;
        const float* src = cb + ((size_t)q * K_ + c * 64) * dd_;
        unsigned short* dst = panels + (size_t)(q * NCHUNK + c) * 16384;
        #pragma unroll
        for (int i = 0; i < 4; i++) {
            int sid = i * 256 + t;
            int n = sid >> 4, j = sid & 15;
            const float* sp = src + n * dd_ + j * 8;
            f32x4 v0 = *(const f32x4*)sp;
            f32x4 v1 = *(const f32x4*)(sp + 4);
            float xs[8] = {v0.x, v0.y, v0.z, v0.w, v1.x, v1.y, v1.z, v1.w};
            unsigned hu[8], lu[8];
            float ss = 0.0f;
            #pragma unroll
            for (int e = 0; e < 8; e++) {
                float xv = -xs[e];                     // NEGATED codeword
                ss = fmaf(xv, xv, ss);
                unsigned u = f2u(xv);
                hu[e] = u;
                float r = xv - bf2f((unsigned short)(u >> 16));
                lu[e] = f2u(r);
            }
            int slot = j ^ (n & 15);
            u32x4 H, L;
            H.x = (hu[0] >> 16) | (hu[1] & 0xFFFF0000u);
            H.y = (hu[2] >> 16) | (hu[3] & 0xFFFF0000u);
            H.z = (hu[4] >> 16) | (hu[5] & 0xFFFF0000u);
            H.w = (hu[6] >> 16) | (hu[7] & 0xFFFF0000u);
            L.x = (lu[0] >> 16) | (lu[1] & 0xFFFF0000u);
            L.y = (lu[2] >> 16) | (lu[3] & 0xFFFF0000u);
            L.z = (lu[4] >> 16) | (lu[5] & 0xFFFF0000u);
            L.w = (lu[6] >> 16) | (lu[7] & 0xFFFF0000u);
            *(u32x4*)&dst[(n * 16 + slot) * 8]        = H;
            *(u32x4*)&dst[8192 + (n * 16 + slot) * 8] = L;
            ss += __shfl_xor(ss, 1, 64);
            ss += __shfl_xor(ss, 2, 64);
            ss += __shfl_xor(ss, 4, 64);
            ss += __shfl_xor(ss, 8, 64);
            if (j == 0) c2h[q * K_ + c * 64 + n] = 0.5f * ss;
        }
    } else {
        // ---- input rmsnorm + sub-vector x2/2 ----
        int row = bid - NCHUNK * Q_;
        const float4 v = *(const float4*)(x + (size_t)row * D_ + t * 4);
        float ss = v.x * v.x + v.y * v.y + v.z * v.z + v.w * v.w;
        #pragma unroll
        for (int o = 32; o > 0; o >>= 1) ss += __shfl_xor(ss, o, 64);
        __shared__ float acc[4];
        if ((t & 63) == 0) acc[t >> 6] = ss;
        __syncthreads();
        float tot = (acc[0] + acc[1]) + (acc[2] + acc[3]);
        float sc  = 1.0f / sqrtf(tot * (1.0f / D_) + 1e-5f);
        const float4 wv = *(const float4*)(w + t * 4);
        float4 o;
        o.x = v.x * sc * wv.x; o.y = v.y * sc * wv.y;
        o.z = v.z * sc * wv.z; o.w = v.w * sc * wv.w;
        *(float4*)(xn + (size_t)row * D_ + t * 4) = o;
        float so = o.x * o.x + o.y * o.y + o.z * o.z + o.w * o.w;
        so += __shfl_xor(so, 1, 64);
        so += __shfl_xor(so, 2, 64);
        so += __shfl_xor(so, 4, 64);
        so += __shfl_xor(so, 8, 64);
        so += __shfl_xor(so, 16, 64);
        if ((t & 31) == 0) x2h[row * Q_ + (t >> 5)] = 0.5f * so;
    }
}

// ---------------- 3-pass split-bf16 MFMA distance + packed-u32 top-2 argmin ----------------
// acc init = x2/2 + c2/2, B negated -> acc_final = d2/2 >= 0; pack (score&~0x7F)|tag, u32 mins.
__launch_bounds__(256, 2)
__global__ void k_dist(const float* __restrict__ xn, const unsigned short* __restrict__ panels,
                       const float* __restrict__ c2h, const float* __restrict__ x2h,
                       int* __restrict__ idxi, float* __restrict__ idxf) {
    __shared__ char smem[65536];   // 2 x 32KB staging; reduce scratch overlaid after loop

    const int t    = threadIdx.x;
    const int lane = t & 63, wave = t >> 6;
    const int wm = wave >> 1, wn = wave & 1;
    const int col = lane & 15, quad = lane >> 4;
    const int q = blockIdx.y;
    const int row0 = blockIdx.x * 128;

    // A fragments (trunc split)
    bf16x8 ah[4][4], al[4][4];
    #pragma unroll
    for (int mt = 0; mt < 4; mt++) {
        #pragma unroll
        for (int kt = 0; kt < 4; kt++) {
            const float* ap = xn + (size_t)(row0 + wm * 64 + mt * 16 + col) * D_
                              + q * dd_ + kt * 32 + quad * 8;
            f32x4 v0 = *(const f32x4*)ap;
            f32x4 v1 = *(const f32x4*)(ap + 4);
            #pragma unroll
            for (int e = 0; e < 8; e++) {
                float xv = (e < 4) ? v0[e] : v1[e - 4];
                unsigned short hh = (unsigned short)(f2u(xv) >> 16);
                float r = xv - bf2f(hh);
                ah[mt][kt][e] = (short)hh;
                al[mt][kt][e] = (short)(unsigned short)(f2u(r) >> 16);
            }
        }
    }

    // per-slot row halves of ||x_q||^2
    f32x4 x2v[4];
    #pragma unroll
    for (int mt = 0; mt < 4; mt++)
        #pragma unroll
        for (int r = 0; r < 4; r++)
            x2v[mt][r] = x2h[(size_t)(row0 + wm * 64 + mt * 16 + quad * 4 + r) * Q_ + q];

    unsigned m1[16], m2[16];
    #pragma unroll
    for (int i = 0; i < 16; i++) { m1[i] = 0xFFFFFFFFu; m2[i] = 0xFFFFFFFFu; }

    const size_t panq = (size_t)q * NCHUNK * 16384;
    const float* c2hq = c2h + q * K_;

    // preload chunk 0 staging + its c2h
    {
        const unsigned short* src = panels + panq;
        #pragma unroll
        for (int i = 0; i < 8; i++) {
            int boff = i * 4096 + t * 16;
            __builtin_amdgcn_global_load_lds((gas_p)((const char*)src + boff),
                                             (las_p)(smem + boff), 16, 0, 0);
        }
    }
    float ch0 = c2hq[wn * 32 + col];
    float ch1 = c2hq[wn * 32 + col + 16];

    for (int c = 0; c < NCHUNK; c++) {
        __syncthreads();
        if (c + 1 < NCHUNK) {
            const unsigned short* src = panels + panq + (size_t)(c + 1) * 16384;
            char* stage = smem + ((c + 1) & 1) * 32768;
            #pragma unroll
            for (int i = 0; i < 8; i++) {
                int boff = i * 4096 + t * 16;
                __builtin_amdgcn_global_load_lds((gas_p)((const char*)src + boff),
                                                 (las_p)(stage + boff), 16, 0, 0);
            }
        }
        float ch0n = 0.0f, ch1n = 0.0f;
        if (c + 1 < NCHUNK) {
            ch0n = c2hq[(c + 1) * 64 + wn * 32 + col];
            ch1n = c2hq[(c + 1) * 64 + wn * 32 + col + 16];
        }
        const char* cbuf = smem + (c & 1) * 32768;

        f32x4 acc[4][2];
        #pragma unroll
        for (int mt = 0; mt < 4; mt++) {
            acc[mt][0] = x2v[mt] + ch0;   // d2/2 accumulator init
            acc[mt][1] = x2v[mt] + ch1;
        }

        #pragma unroll
        for (int kt = 0; kt < 4; kt++) {
            const int sw = ((quad + kt * 4) ^ col) * 16;
            const int a0 = (wn * 32 + col) * 256 + sw;
            const int a1 = (wn * 32 + 16 + col) * 256 + sw;
            bf16x8 bh0 = *(const bf16x8*)(cbuf + a0);
            bf16x8 bh1 = *(const bf16x8*)(cbuf + a1);
            bf16x8 bl0 = *(const bf16x8*)(cbuf + 16384 + a0);
            bf16x8 bl1 = *(const bf16x8*)(cbuf + 16384 + a1);
            #pragma unroll
            for (int mt = 0; mt < 4; mt++) {
                acc[mt][0] = __builtin_amdgcn_mfma_f32_16x16x32_bf16(ah[mt][kt], bh0, acc[mt][0], 0, 0, 0);
                acc[mt][1] = __builtin_amdgcn_mfma_f32_16x16x32_bf16(ah[mt][kt], bh1, acc[mt][1], 0, 0, 0);
                acc[mt][0] = __builtin_amdgcn_mfma_f32_16x16x32_bf16(al[mt][kt], bh0, acc[mt][0], 0, 0, 0);
                acc[mt][1] = __builtin_amdgcn_mfma_f32_16x16x32_bf16(al[mt][kt], bh1, acc[mt][1], 0, 0, 0);
                acc[mt][0] = __builtin_amdgcn_mfma_f32_16x16x32_bf16(ah[mt][kt], bl0, acc[mt][0], 0, 0, 0);
                acc[mt][1] = __builtin_amdgcn_mfma_f32_16x16x32_bf16(ah[mt][kt], bl1, acc[mt][1], 0, 0, 0);
            }
        }

        const unsigned tg0 = (unsigned)(c << 1), tg1 = tg0 | 1u;
        #pragma unroll
        for (int mt = 0; mt < 4; mt++) {
            #pragma unroll
            for (int r = 0; r < 4; r++) {
                const int sl = mt * 4 + r;
                unsigned p0 = (f2u(acc[mt][0][r]) & 0xFFFFFF80u) | tg0;
                m2[sl] = umin_(m2[sl], umax_(m1[sl], p0));
                m1[sl] = umin_(m1[sl], p0);
                unsigned p1 = (f2u(acc[mt][1][r]) & 0xFFFFFF80u) | tg1;
                m2[sl] = umin_(m2[sl], umax_(m1[sl], p1));
                m1[sl] = umin_(m1[sl], p1);
            }
        }
        ch0 = ch0n; ch1 = ch1n;
    }

    // cross-lane top-2 merge per row (u32 domain; stride 33)
    __syncthreads();
    unsigned* rm1 = (unsigned*)smem;             // [128][33]
    unsigned* rm2 = (unsigned*)(smem + 16896);
    #pragma unroll
    for (int mt = 0; mt < 4; mt++) {
        #pragma unroll
        for (int r = 0; r < 4; r++) {
            int sl = mt * 4 + r;
            int row_l = wm * 64 + mt * 16 + quad * 4 + r;
            int e = wn * 16 + col;
            rm1[row_l * 33 + e] = m1[sl];
            rm2[row_l * 33 + e] = m2[sl];
        }
    }
    __syncthreads();
    if (t < 128) {
        unsigned b1 = 0xFFFFFFFFu, b2 = 0xFFFFFFFFu;
        int be = 0;
        for (int e = 0; e < 32; e++) {
            unsigned v1 = rm1[t * 33 + e], v2 = rm2[t * 33 + e];
            b2 = umin_(b2, v2);
            if (v1 < b1) { b2 = umin_(b2, b1); b1 = v1; be = e; }
            else         { b2 = umin_(b2, v1); }
        }
        int tag = (int)(b1 & 0x7Fu);
        int k = ((tag >> 1) << 6) | ((be >> 4) << 5) | ((tag & 1) << 4) | (be & 15);
        float f1 = u2f(b1 & 0xFFFFFF80u);
        float f2 = u2f(b2 & 0xFFFFFF80u);
        bool flag = (f2 - f1) < TAU;   // quantized ties -> gap 0 -> rescued
        int rg = row0 + t;
        idxi[rg * Q_ + q] = k | (flag ? (int)0x80000000 : 0);
        idxf[rg * Q_ + q] = (float)k;
    }
}

// ---------------- gather + output rmsnorm, with inline exact rescue for flagged (row,q) ----
__global__ void k_out(const float* __restrict__ cb, const float* __restrict__ c2h,
                      float* xo /* xn in, out out (same buffer) */,
                      const int* __restrict__ idxi, const float* __restrict__ w,
                      float* __restrict__ idxf) {
    const int row = blockIdx.x, t = threadIdx.x;
    __shared__ int   sidx[Q_];
    __shared__ int   anyflag;
    __shared__ float xq[dd_];
    __shared__ float bs_sh[256];
    __shared__ int   bk_sh[256];
    __shared__ float racc[4];
    if (t == 0) anyflag = 0;
    __syncthreads();
    if (t < Q_) {
        int v = idxi[row * Q_ + t];
        sidx[t] = v & 0xFFF;
        if (v < 0) atomicOr(&anyflag, 1 << t);
    }
    __syncthreads();
    int flags = anyflag;
    while (flags) {
        int q = __ffs(flags) - 1;
        flags &= flags - 1;
        if (t < dd_) xq[t] = xo[(size_t)row * D_ + q * dd_ + t];
        __syncthreads();
        float bs = FLT_MAX; int bk = 0;
        for (int i = 0; i < 16; i++) {
            int k = i * 256 + t;
            const float* cp = cb + ((size_t)q * K_ + k) * dd_;
            float dot = 0.0f;
            #pragma unroll 8
            for (int d = 0; d < dd_; d += 4) {
                f32x4 cv = *(const f32x4*)(cp + d);
                dot = fmaf(cv.x, xq[d],     dot);
                dot = fmaf(cv.y, xq[d + 1], dot);
                dot = fmaf(cv.z, xq[d + 2], dot);
                dot = fmaf(cv.w, xq[d + 3], dot);
            }
            float s = c2h[q * K_ + k] - dot;   // d2/2 - x2/2 (monotone in d2)
            if (s < bs || (s == bs && k < bk)) { bs = s; bk = k; }
        }
        bs_sh[t] = bs; bk_sh[t] = bk;
        __syncthreads();
        if (t == 0) {
            float B = FLT_MAX; int K2 = 0x7fffffff;
            for (int e = 0; e < 256; e++) {
                if (bs_sh[e] < B || (bs_sh[e] == B && bk_sh[e] < K2)) { B = bs_sh[e]; K2 = bk_sh[e]; }
            }
            sidx[q] = K2;
            idxf[row * Q_ + q] = (float)K2;
        }
        __syncthreads();
    }

    // gather + rmsnorm (reads of xo complete before writes via barrier above)
    int col = t * 4;
    int q   = col >> 7;
    int dc  = col & 127;
    const float4 v = *(const float4*)(cb + ((size_t)q * K_ + sidx[q]) * dd_ + dc);
    float ss = v.x * v.x + v.y * v.y + v.z * v.z + v.w * v.w;
    #pragma unroll
    for (int o = 32; o > 0; o >>= 1) ss += __shfl_xor(ss, o, 64);
    if ((t & 63) == 0) racc[t >> 6] = ss;
    __syncthreads();
    float tot = (racc[0] + racc[1]) + (racc[2] + racc[3]);
    float sc  = 1.0f / sqrtf(tot * (1.0f / D_) + 1e-5f);
    const float4 wv = *(const float4*)(w + col);
    float4 o;
    o.x = v.x * sc * wv.x; o.y = v.y * sc * wv.y;
    o.z = v.z * sc * wv.z; o.w = v.w * sc * wv.w;
    *(float4*)(xo + (size_t)row * D_ + col) = o;
}

extern "C" void kernel_launch(void* const* d_in, const int* in_sizes, int n_in,
                              void* d_out, int out_size, void* d_ws, size_t ws_size,
                              hipStream_t stream) {
    const float* x     = (const float*)d_in[0];
    const float* cb    = (const float*)d_in[1];
    const float* w_in  = (const float*)d_in[2];
    const float* w_out = (const float*)d_in[3];

    float* out  = (float*)d_out;                  // xn lives here between k_prep and k_out
    float* idxf = out + (size_t)ROWS * D_;

    // ws: panels 16MB | c2h 128KB | x2h 256KB | idxi 256KB
    unsigned short* panels = (unsigned short*)d_ws;
    float* c2h = (float*)((char*)d_ws + (16u << 20));
    float* x2h = c2h + Q_ * K_;
    int*   idxi = (int*)(x2h + (size_t)ROWS * Q_);

    k_prep<<<dim3(NCHUNK * Q_ + ROWS), 256, 0, stream>>>(cb, x, w_in, out, panels, c2h, x2h);
    k_dist<<<dim3(ROWS / 128, Q_),     256, 0, stream>>>(out, panels, c2h, x2h, idxi, idxf);
    k_out <<<dim3(ROWS),               256, 0, stream>>>(cb, c2h, out, idxi, w_out, idxf);
}

// Round 5
// 342.144 us; speedup vs baseline: 1.4671x; 1.4671x over previous
//
#include <hip/hip_runtime.h>
#include <math.h>
#include <float.h>

// VideoQuantizer: rmsnorm -> per-subvector argmin over 4096 codewords -> gather -> rmsnorm
// B=8 T=1024 D=1024 Q=8 K=4096 d=128
#define Q_     8
#define K_     4096
#define dd_    128
#define D_     1024
#define ROWS   8192
#define NCHUNK 64
#define TAU    0.01f   // rescue threshold on d2/2 scale (split err ~5e-3 + quant ~4e-3 < 0.01+margin)

typedef __attribute__((ext_vector_type(8))) short bf16x8;
typedef __attribute__((ext_vector_type(4))) float f32x4;
typedef __attribute__((ext_vector_type(4))) unsigned int u32x4;

typedef const __attribute__((address_space(1))) unsigned int* gas_p;
typedef __attribute__((address_space(3))) unsigned int* las_p;

__device__ inline float bf2f(unsigned short h) {
    union { unsigned u; float f; } v; v.u = ((unsigned)h) << 16; return v.f;
}
__device__ inline unsigned f2u(float x) { union { float f; unsigned u; } v; v.f = x; return v.u; }
__device__ inline float u2f(unsigned x) { union { unsigned u; float f; } v; v.u = x; return v.f; }
__device__ inline unsigned umin_(unsigned a, unsigned b) { return a < b ? a : b; }
__device__ inline unsigned umax_(unsigned a, unsigned b) { return a > b ? a : b; }

// ---------------- fused: panel build (neg, hi/lo trunc split) + c2/2 | input rmsnorm + x2/2 ----
// panels[q][c][plane][n][slot][8 bf16] of NEGATED codewords; slot = j ^ (n&15)
__global__ void k_prep(const float* __restrict__ cb, const float* __restrict__ x,
                       const float* __restrict__ w, float* __restrict__ xn,
                       unsigned short* __restrict__ panels, float* __restrict__ c2h,
                       float* __restrict__ x2h, int* __restrict__ counter) {
    const int bid = blockIdx.x, t = threadIdx.x;
    if (bid == 0 && t == 0) *counter = 0;
    if (bid < NCHUNK * Q_) {
        // ---- panel prep ----
        int c = bid & 63, q = bid >> 6;
        const float* src = cb + ((size_t)q * K_ + c * 64) * dd_;
        unsigned short* dst = panels + (size_t)(q * NCHUNK + c) * 16384;
        #pragma unroll
        for (int i = 0; i < 4; i++) {
            int sid = i * 256 + t;
            int n = sid >> 4, j = sid & 15;
            const float* sp = src + n * dd_ + j * 8;
            f32x4 v0 = *(const f32x4*)sp;
            f32x4 v1 = *(const f32x4*)(sp + 4);
            float xs[8] = {v0.x, v0.y, v0.z, v0.w, v1.x, v1.y, v1.z, v1.w};
            unsigned hu[8], lu[8];
            float ss = 0.0f;
            #pragma unroll
            for (int e = 0; e < 8; e++) {
                float xv = -xs[e];                     // NEGATED codeword
                ss = fmaf(xv, xv, ss);
                unsigned u = f2u(xv);
                hu[e] = u;
                float r = xv - bf2f((unsigned short)(u >> 16));
                lu[e] = f2u(r);
            }
            int slot = j ^ (n & 15);
            u32x4 H, L;
            H.x = (hu[0] >> 16) | (hu[1] & 0xFFFF0000u);
            H.y = (hu[2] >> 16) | (hu[3] & 0xFFFF0000u);
            H.z = (hu[4] >> 16) | (hu[5] & 0xFFFF0000u);
            H.w = (hu[6] >> 16) | (hu[7] & 0xFFFF0000u);
            L.x = (lu[0] >> 16) | (lu[1] & 0xFFFF0000u);
            L.y = (lu[2] >> 16) | (lu[3] & 0xFFFF0000u);
            L.z = (lu[4] >> 16) | (lu[5] & 0xFFFF0000u);
            L.w = (lu[6] >> 16) | (lu[7] & 0xFFFF0000u);
            *(u32x4*)&dst[(n * 16 + slot) * 8]        = H;
            *(u32x4*)&dst[8192 + (n * 16 + slot) * 8] = L;
            ss += __shfl_xor(ss, 1, 64);
            ss += __shfl_xor(ss, 2, 64);
            ss += __shfl_xor(ss, 4, 64);
            ss += __shfl_xor(ss, 8, 64);
            if (j == 0) c2h[q * K_ + c * 64 + n] = 0.5f * ss;
        }
    } else {
        // ---- input rmsnorm + sub-vector x2/2 ----
        int row = bid - NCHUNK * Q_;
        const float4 v = *(const float4*)(x + (size_t)row * D_ + t * 4);
        float ss = v.x * v.x + v.y * v.y + v.z * v.z + v.w * v.w;
        #pragma unroll
        for (int o = 32; o > 0; o >>= 1) ss += __shfl_xor(ss, o, 64);
        __shared__ float acc[4];
        if ((t & 63) == 0) acc[t >> 6] = ss;
        __syncthreads();
        float tot = (acc[0] + acc[1]) + (acc[2] + acc[3]);
        float sc  = 1.0f / sqrtf(tot * (1.0f / D_) + 1e-5f);
        const float4 wv = *(const float4*)(w + t * 4);
        float4 o;
        o.x = v.x * sc * wv.x; o.y = v.y * sc * wv.y;
        o.z = v.z * sc * wv.z; o.w = v.w * sc * wv.w;
        *(float4*)(xn + (size_t)row * D_ + t * 4) = o;
        float so = o.x * o.x + o.y * o.y + o.z * o.z + o.w * o.w;
        so += __shfl_xor(so, 1, 64);
        so += __shfl_xor(so, 2, 64);
        so += __shfl_xor(so, 4, 64);
        so += __shfl_xor(so, 8, 64);
        so += __shfl_xor(so, 16, 64);
        if ((t & 31) == 0) x2h[row * Q_ + (t >> 5)] = 0.5f * so;
    }
}

// ---------------- 3-pass split-bf16 MFMA distance + packed-u32 top-2 argmin ----------------
// acc init = x2/2 + c2/2, B negated -> acc_final = d2/2 >= 0; pack (score&~0x7F)|tag, u32 mins.
// Flagged near-ties appended to (counter, list) for the separate exact rescue kernel.
__launch_bounds__(256, 2)
__global__ void k_dist(const float* __restrict__ xn, const unsigned short* __restrict__ panels,
                       const float* __restrict__ c2h, const float* __restrict__ x2h,
                       int* __restrict__ idxi, float* __restrict__ idxf,
                       int* __restrict__ list, int* __restrict__ counter) {
    __shared__ char smem[65536];   // 2 x 32KB staging; reduce scratch overlaid after loop

    const int t    = threadIdx.x;
    const int lane = t & 63, wave = t >> 6;
    const int wm = wave >> 1, wn = wave & 1;
    const int col = lane & 15, quad = lane >> 4;
    const int q = blockIdx.y;
    const int row0 = blockIdx.x * 128;

    // A fragments (trunc split)
    bf16x8 ah[4][4], al[4][4];
    #pragma unroll
    for (int mt = 0; mt < 4; mt++) {
        #pragma unroll
        for (int kt = 0; kt < 4; kt++) {
            const float* ap = xn + (size_t)(row0 + wm * 64 + mt * 16 + col) * D_
                              + q * dd_ + kt * 32 + quad * 8;
            f32x4 v0 = *(const f32x4*)ap;
            f32x4 v1 = *(const f32x4*)(ap + 4);
            #pragma unroll
            for (int e = 0; e < 8; e++) {
                float xv = (e < 4) ? v0[e] : v1[e - 4];
                unsigned short hh = (unsigned short)(f2u(xv) >> 16);
                float r = xv - bf2f(hh);
                ah[mt][kt][e] = (short)hh;
                al[mt][kt][e] = (short)(unsigned short)(f2u(r) >> 16);
            }
        }
    }

    // per-slot row halves of ||x_q||^2
    f32x4 x2v[4];
    #pragma unroll
    for (int mt = 0; mt < 4; mt++)
        #pragma unroll
        for (int r = 0; r < 4; r++)
            x2v[mt][r] = x2h[(size_t)(row0 + wm * 64 + mt * 16 + quad * 4 + r) * Q_ + q];

    unsigned m1[16], m2[16];
    #pragma unroll
    for (int i = 0; i < 16; i++) { m1[i] = 0xFFFFFFFFu; m2[i] = 0xFFFFFFFFu; }

    const size_t panq = (size_t)q * NCHUNK * 16384;
    const float* c2hq = c2h + q * K_;

    // preload chunk 0 staging
    {
        const unsigned short* src = panels + panq;
        #pragma unroll
        for (int i = 0; i < 8; i++) {
            int boff = i * 4096 + t * 16;
            __builtin_amdgcn_global_load_lds((gas_p)((const char*)src + boff),
                                             (las_p)(smem + boff), 16, 0, 0);
        }
    }
    float ch0 = c2hq[wn * 32 + col];
    float ch1 = c2hq[wn * 32 + col + 16];

    for (int c = 0; c < NCHUNK; c++) {
        __syncthreads();
        if (c + 1 < NCHUNK) {
            const unsigned short* src = panels + panq + (size_t)(c + 1) * 16384;
            char* stage = smem + ((c + 1) & 1) * 32768;
            #pragma unroll
            for (int i = 0; i < 8; i++) {
                int boff = i * 4096 + t * 16;
                __builtin_amdgcn_global_load_lds((gas_p)((const char*)src + boff),
                                                 (las_p)(stage + boff), 16, 0, 0);
            }
        }
        float ch0n = 0.0f, ch1n = 0.0f;
        if (c + 1 < NCHUNK) {
            ch0n = c2hq[(c + 1) * 64 + wn * 32 + col];
            ch1n = c2hq[(c + 1) * 64 + wn * 32 + col + 16];
        }
        const char* cbuf = smem + (c & 1) * 32768;

        f32x4 acc[4][2];
        #pragma unroll
        for (int mt = 0; mt < 4; mt++) {
            acc[mt][0] = x2v[mt] + ch0;   // d2/2 accumulator init
            acc[mt][1] = x2v[mt] + ch1;
        }

        #pragma unroll
        for (int kt = 0; kt < 4; kt++) {
            const int sw = ((quad + kt * 4) ^ col) * 16;
            const int a0 = (wn * 32 + col) * 256 + sw;
            const int a1 = (wn * 32 + 16 + col) * 256 + sw;
            bf16x8 bh0 = *(const bf16x8*)(cbuf + a0);
            bf16x8 bh1 = *(const bf16x8*)(cbuf + a1);
            bf16x8 bl0 = *(const bf16x8*)(cbuf + 16384 + a0);
            bf16x8 bl1 = *(const bf16x8*)(cbuf + 16384 + a1);
            #pragma unroll
            for (int mt = 0; mt < 4; mt++) {
                acc[mt][0] = __builtin_amdgcn_mfma_f32_16x16x32_bf16(ah[mt][kt], bh0, acc[mt][0], 0, 0, 0);
                acc[mt][1] = __builtin_amdgcn_mfma_f32_16x16x32_bf16(ah[mt][kt], bh1, acc[mt][1], 0, 0, 0);
                acc[mt][0] = __builtin_amdgcn_mfma_f32_16x16x32_bf16(al[mt][kt], bh0, acc[mt][0], 0, 0, 0);
                acc[mt][1] = __builtin_amdgcn_mfma_f32_16x16x32_bf16(al[mt][kt], bh1, acc[mt][1], 0, 0, 0);
                acc[mt][0] = __builtin_amdgcn_mfma_f32_16x16x32_bf16(ah[mt][kt], bl0, acc[mt][0], 0, 0, 0);
                acc[mt][1] = __builtin_amdgcn_mfma_f32_16x16x32_bf16(ah[mt][kt], bl1, acc[mt][1], 0, 0, 0);
            }
        }

        const unsigned tg0 = (unsigned)(c << 1), tg1 = tg0 | 1u;
        #pragma unroll
        for (int mt = 0; mt < 4; mt++) {
            #pragma unroll
            for (int r = 0; r < 4; r++) {
                const int sl = mt * 4 + r;
                unsigned p0 = (f2u(acc[mt][0][r]) & 0xFFFFFF80u) | tg0;
                m2[sl] = umin_(m2[sl], umax_(m1[sl], p0));
                m1[sl] = umin_(m1[sl], p0);
                unsigned p1 = (f2u(acc[mt][1][r]) & 0xFFFFFF80u) | tg1;
                m2[sl] = umin_(m2[sl], umax_(m1[sl], p1));
                m1[sl] = umin_(m1[sl], p1);
            }
        }
        ch0 = ch0n; ch1 = ch1n;
    }

    // cross-lane top-2 merge per row (u32 domain; stride 33)
    __syncthreads();
    unsigned* rm1 = (unsigned*)smem;             // [128][33]
    unsigned* rm2 = (unsigned*)(smem + 16896);
    #pragma unroll
    for (int mt = 0; mt < 4; mt++) {
        #pragma unroll
        for (int r = 0; r < 4; r++) {
            int sl = mt * 4 + r;
            int row_l = wm * 64 + mt * 16 + quad * 4 + r;
            int e = wn * 16 + col;
            rm1[row_l * 33 + e] = m1[sl];
            rm2[row_l * 33 + e] = m2[sl];
        }
    }
    __syncthreads();
    if (t < 128) {
        unsigned b1 = 0xFFFFFFFFu, b2 = 0xFFFFFFFFu;
        int be = 0;
        for (int e = 0; e < 32; e++) {
            unsigned v1 = rm1[t * 33 + e], v2 = rm2[t * 33 + e];
            b2 = umin_(b2, v2);
            if (v1 < b1) { b2 = umin_(b2, b1); b1 = v1; be = e; }
            else         { b2 = umin_(b2, v1); }
        }
        int tag = (int)(b1 & 0x7Fu);
        int k = ((tag >> 1) << 6) | ((be >> 4) << 5) | ((tag & 1) << 4) | (be & 15);
        float f1 = u2f(b1 & 0xFFFFFF80u);
        float f2 = u2f(b2 & 0xFFFFFF80u);
        int rg = row0 + t;
        idxi[rg * Q_ + q] = k;
        idxf[rg * Q_ + q] = (float)k;
        if (f2 - f1 < TAU) {                 // quantized ties -> gap 0 -> always rescued
            int p = atomicAdd(counter, 1);
            list[p] = rg * Q_ + q;
        }
    }
}

// ---------------- exact fp32 re-score of flagged (row,q) pairs (grid-stride, parallel) ----
__global__ void k_rescue(const float* __restrict__ xn, const float* __restrict__ cb,
                         const float* __restrict__ c2h, const int* __restrict__ list,
                         const int* __restrict__ counter, int* __restrict__ idxi,
                         float* __restrict__ idxf) {
    __shared__ float xq[dd_];
    __shared__ float bs_sh[256];
    __shared__ int   bk_sh[256];
    const int n = *counter;
    const int t = threadIdx.x;
    for (int it = blockIdx.x; it < n; it += gridDim.x) {
        __syncthreads();
        int item = list[it];
        int rg = item >> 3, q = item & 7;
        if (t < dd_) xq[t] = xn[(size_t)rg * D_ + q * dd_ + t];
        __syncthreads();
        float bs = FLT_MAX; int bk = 0x7fffffff;
        for (int i = 0; i < 16; i++) {
            int k = i * 256 + t;
            const float* cp = cb + ((size_t)q * K_ + k) * dd_;
            float dot = 0.0f;
            #pragma unroll 8
            for (int d = 0; d < dd_; d += 4) {
                f32x4 cv = *(const f32x4*)(cp + d);
                dot = fmaf(cv.x, xq[d],     dot);
                dot = fmaf(cv.y, xq[d + 1], dot);
                dot = fmaf(cv.z, xq[d + 2], dot);
                dot = fmaf(cv.w, xq[d + 3], dot);
            }
            float s = c2h[q * K_ + k] - dot;   // d2/2 - x2/2 (monotone in d2)
            if (s < bs || (s == bs && k < bk)) { bs = s; bk = k; }
        }
        bs_sh[t] = bs; bk_sh[t] = bk;
        __syncthreads();
        if (t == 0) {
            float B = FLT_MAX; int K2 = 0x7fffffff;
            for (int e = 0; e < 256; e++) {
                if (bs_sh[e] < B || (bs_sh[e] == B && bk_sh[e] < K2)) { B = bs_sh[e]; K2 = bk_sh[e]; }
            }
            idxi[item] = K2;
            idxf[item] = (float)K2;
        }
    }
}

// ---------------- gather + output rmsnorm ----------------
__global__ void k_out(const float* __restrict__ cb, const int* __restrict__ idx_i,
                      const float* __restrict__ w, float* __restrict__ out) {
    int row = blockIdx.x;
    int t   = threadIdx.x;
    __shared__ int   sidx[Q_];
    __shared__ float acc[4];
    if (t < Q_) sidx[t] = idx_i[row * Q_ + t];
    __syncthreads();
    int col = t * 4;
    int q   = col >> 7;
    int dc  = col & 127;
    const float4 v = *(const float4*)(cb + ((size_t)q * K_ + sidx[q]) * dd_ + dc);
    float ss = v.x * v.x + v.y * v.y + v.z * v.z + v.w * v.w;
    #pragma unroll
    for (int o = 32; o > 0; o >>= 1) ss += __shfl_xor(ss, o, 64);
    if ((t & 63) == 0) acc[t >> 6] = ss;
    __syncthreads();
    float tot = (acc[0] + acc[1]) + (acc[2] + acc[3]);
    float sc  = 1.0f / sqrtf(tot * (1.0f / D_) + 1e-5f);
    const float4 wv = *(const float4*)(w + col);
    float4 o;
    o.x = v.x * sc * wv.x; o.y = v.y * sc * wv.y;
    o.z = v.z * sc * wv.z; o.w = v.w * sc * wv.w;
    *(float4*)(out + (size_t)row * D_ + col) = o;
}

extern "C" void kernel_launch(void* const* d_in, const int* in_sizes, int n_in,
                              void* d_out, int out_size, void* d_ws, size_t ws_size,
                              hipStream_t stream) {
    const float* x     = (const float*)d_in[0];
    const float* cb    = (const float*)d_in[1];
    const float* w_in  = (const float*)d_in[2];
    const float* w_out = (const float*)d_in[3];

    float* out  = (float*)d_out;                  // xn lives here between k_prep and k_out
    float* idxf = out + (size_t)ROWS * D_;

    // ws: panels 16MB | c2h 128KB | x2h 256KB | idxi 256KB | list 256KB | counter
    unsigned short* panels = (unsigned short*)d_ws;
    float* c2h  = (float*)((char*)d_ws + (16u << 20));
    float* x2h  = c2h + Q_ * K_;
    int*   idxi = (int*)(x2h + (size_t)ROWS * Q_);
    int*   list = idxi + ROWS * Q_;
    int*   counter = list + ROWS * Q_;

    k_prep  <<<dim3(NCHUNK * Q_ + ROWS), 256, 0, stream>>>(cb, x, w_in, out, panels, c2h, x2h, counter);
    k_dist  <<<dim3(ROWS / 128, Q_),     256, 0, stream>>>(out, panels, c2h, x2h, idxi, idxf, list, counter);
    k_rescue<<<dim3(1024),               256, 0, stream>>>(out, cb, c2h, list, counter, idxi, idxf);
    k_out   <<<dim3(ROWS),               256, 0, stream>>>(cb, idxi, w_out, out);
}